// Round 1
// baseline (1216.423 us; speedup 1.0000x reference)
//
#include <hip/hip_runtime.h>

#define IN_CH 128
#define HID 48
#define OUT_CH 16
#define NEG_SLOPE 0.2f

__device__ __forceinline__ unsigned fenc(float f) {
    unsigned u = __float_as_uint(f);
    return (u & 0x80000000u) ? ~u : (u | 0x80000000u);
}
__device__ __forceinline__ float fdec(unsigned u) {
    u = (u & 0x80000000u) ? (u & 0x7fffffffu) : ~u;
    return __uint_as_float(u);
}
__device__ __forceinline__ float leaky(float x) { return x >= 0.f ? x : NEG_SLOPE * x; }
__device__ __forceinline__ float elu(float x) { return x > 0.f ? x : expf(x) - 1.f; }

// Edge index fetch that tolerates either int32 or int64 storage.
__device__ __forceinline__ void load_edge(const void* ei, int E, int is64, int e,
                                          int& s, int& d) {
    if (is64) {
        const long long* p = (const long long*)ei;
        s = (int)p[e];
        d = (int)p[(size_t)E + e];
    } else {
        const int* p = (const int*)ei;
        s = p[e];
        d = p[(size_t)E + e];
    }
}

// Detect int64 vs int32 edge_index: for int64 little-endian values < 2^31,
// every odd 32-bit word is 0. For int32 random node ids, OR of 64 of them != 0.
__global__ void k_detect(const unsigned* __restrict__ ei, int* __restrict__ flag) {
    if (threadIdx.x == 0 && blockIdx.x == 0) {
        unsigned s = 0;
        for (int i = 1; i < 128; i += 2) s |= ei[i];
        *flag = (s == 0) ? 1 : 0;
    }
}

// K1: h = x @ W. Block handles 256 nodes; thread: 4 nodes x 12 k register tile.
#define BLK_NODES 256
__global__ __launch_bounds__(256, 2) void k_xw(const float* __restrict__ x,
                                               const float* __restrict__ W,
                                               float* __restrict__ h, int N) {
    __shared__ float Wl[IN_CH * HID];        // 24576 B
    __shared__ float xl[BLK_NODES * 33];     // 32-c chunk, padded stride 33: 33792 B
    const int t = threadIdx.x;
    for (int i = t; i < IN_CH * HID / 4; i += 256)
        ((float4*)Wl)[i] = ((const float4*)W)[i];
    const int n0 = blockIdx.x * BLK_NODES;
    const int kq = t & 3;        // k quarter: 12 ks
    const int ng = t >> 2;       // node group: 4 nodes
    const int k0 = kq * 12;

    float acc[4][12];
#pragma unroll
    for (int i = 0; i < 4; ++i)
#pragma unroll
        for (int j = 0; j < 12; ++j) acc[i][j] = 0.f;

    for (int c0 = 0; c0 < IN_CH; c0 += 32) {
        __syncthreads();
#pragma unroll
        for (int p = 0; p < 8; ++p) {
            int id = t + p * 256;    // 0..2047
            int row = id >> 3;       // 0..255
            int seg = id & 7;        // 0..7
            int n = n0 + row;
            float4 v = make_float4(0.f, 0.f, 0.f, 0.f);
            if (n < N) v = ((const float4*)(x + (size_t)n * IN_CH + c0))[seg];
            float* dst = &xl[row * 33 + seg * 4];
            dst[0] = v.x; dst[1] = v.y; dst[2] = v.z; dst[3] = v.w;
        }
        __syncthreads();
#pragma unroll 8
        for (int cc = 0; cc < 32; ++cc) {
            int c = c0 + cc;
            float xv[4];
#pragma unroll
            for (int i = 0; i < 4; ++i) xv[i] = xl[(ng * 4 + i) * 33 + cc];
            const float* wr = &Wl[c * HID + k0];
#pragma unroll
            for (int j = 0; j < 12; ++j) {
                float wv = wr[j];
#pragma unroll
                for (int i = 0; i < 4; ++i) acc[i][j] += xv[i] * wv;
            }
        }
    }
#pragma unroll
    for (int i = 0; i < 4; ++i) {
        int n = n0 + ng * 4 + i;
        if (n < N) {
#pragma unroll
            for (int j = 0; j < 12; j += 4) {
                float4 v = make_float4(acc[i][j], acc[i][j + 1], acc[i][j + 2], acc[i][j + 3]);
                *((float4*)(h + (size_t)n * HID + k0 + j)) = v;
            }
        }
    }
}

// K2: per-node attention terms + init running max with self-loop logit.
__global__ __launch_bounds__(256) void k_attn_node(const float* __restrict__ h,
                                                   const float* __restrict__ att_src,
                                                   const float* __restrict__ att_dst,
                                                   float* __restrict__ a_src,
                                                   float* __restrict__ a_dst,
                                                   unsigned* __restrict__ maxenc, int N) {
    int n = blockIdx.x * blockDim.x + threadIdx.x;
    if (n >= N) return;
    const float4* h4 = (const float4*)(h + (size_t)n * HID);
    float as = 0.f, ad = 0.f;
#pragma unroll
    for (int j = 0; j < 12; ++j) {
        float4 v = h4[j];
        as += v.x * att_src[4 * j + 0] + v.y * att_src[4 * j + 1] +
              v.z * att_src[4 * j + 2] + v.w * att_src[4 * j + 3];
        ad += v.x * att_dst[4 * j + 0] + v.y * att_dst[4 * j + 1] +
              v.z * att_dst[4 * j + 2] + v.w * att_dst[4 * j + 3];
    }
    a_src[n] = as;
    a_dst[n] = ad;
    maxenc[n] = fenc(leaky(as + ad));
}

// K3: edge max
__global__ __launch_bounds__(256) void k_edge_max(const void* __restrict__ ei,
                                                  const int* __restrict__ flag,
                                                  const float* __restrict__ a_src,
                                                  const float* __restrict__ a_dst,
                                                  unsigned* __restrict__ maxenc, int E) {
    int e = blockIdx.x * blockDim.x + threadIdx.x;
    if (e >= E) return;
    int is64 = *flag;
    int s, d;
    load_edge(ei, E, is64, e, s, d);
    float l = leaky(a_src[s] + a_dst[d]);
    atomicMax(&maxenc[d], fenc(l));
}

// K4: decode max, init denom with self-loop term
__global__ __launch_bounds__(256) void k_node_denom(const float* __restrict__ a_src,
                                                    const float* __restrict__ a_dst,
                                                    const unsigned* __restrict__ maxenc,
                                                    float* __restrict__ m,
                                                    float* __restrict__ denom, int N) {
    int n = blockIdx.x * blockDim.x + threadIdx.x;
    if (n >= N) return;
    float mm = fdec(maxenc[n]);
    m[n] = mm;
    float sl = leaky(a_src[n] + a_dst[n]);
    denom[n] = expf(sl - mm);
}

// K5: edge exp-sum
__global__ __launch_bounds__(256) void k_edge_sum(const void* __restrict__ ei,
                                                  const int* __restrict__ flag,
                                                  const float* __restrict__ a_src,
                                                  const float* __restrict__ a_dst,
                                                  const float* __restrict__ m,
                                                  float* __restrict__ denom, int E) {
    int e = blockIdx.x * blockDim.x + threadIdx.x;
    if (e >= E) return;
    int is64 = *flag;
    int s, d;
    load_edge(ei, E, is64, e, s, d);
    float l = leaky(a_src[s] + a_dst[d]);
    atomicAdd(&denom[d], expf(l - m[d]));
}

// K6: agg = alpha_self * h  (full overwrite -> also clears poison)
__global__ __launch_bounds__(256) void k_agg_init(const float* __restrict__ h,
                                                  const float* __restrict__ a_src,
                                                  const float* __restrict__ a_dst,
                                                  const float* __restrict__ m,
                                                  const float* __restrict__ denom,
                                                  float* __restrict__ agg, int N) {
    int n = blockIdx.x * blockDim.x + threadIdx.x;
    if (n >= N) return;
    float sl = leaky(a_src[n] + a_dst[n]);
    float alpha = expf(sl - m[n]) / denom[n];
    const float4* h4 = (const float4*)(h + (size_t)n * HID);
    float4* a4 = (float4*)(agg + (size_t)n * HID);
#pragma unroll
    for (int j = 0; j < 12; ++j) {
        float4 v = h4[j];
        a4[j] = make_float4(alpha * v.x, alpha * v.y, alpha * v.z, alpha * v.w);
    }
}

// K7: edge aggregation, 12 threads per edge, 4 channels each.
__global__ __launch_bounds__(256) void k_edge_agg(const void* __restrict__ ei,
                                                  const int* __restrict__ flag,
                                                  const float* __restrict__ a_src,
                                                  const float* __restrict__ a_dst,
                                                  const float* __restrict__ m,
                                                  const float* __restrict__ denom,
                                                  const float* __restrict__ h,
                                                  float* __restrict__ agg, int E) {
    int id = blockIdx.x * blockDim.x + threadIdx.x;
    int e = id / 12;
    int part = id % 12;
    if (e >= E) return;
    int is64 = *flag;
    int s, d;
    load_edge(ei, E, is64, e, s, d);
    float l = leaky(a_src[s] + a_dst[d]);
    float alpha = expf(l - m[d]) / denom[d];
    float4 hv = ((const float4*)h)[(size_t)s * 12 + part];
    float* ap = agg + (size_t)d * HID + part * 4;
    atomicAdd(ap + 0, alpha * hv.x);
    atomicAdd(ap + 1, alpha * hv.y);
    atomicAdd(ap + 2, alpha * hv.z);
    atomicAdd(ap + 3, alpha * hv.w);
}

// K8: out = log_softmax(elu(agg + gat_bias) @ lin_W + lin_b)
__global__ __launch_bounds__(256) void k_out(const float* __restrict__ agg,
                                             const float* __restrict__ gat_bias,
                                             const float* __restrict__ lin_W,
                                             const float* __restrict__ lin_b,
                                             float* __restrict__ out, int N) {
    __shared__ float4 Wl4[HID * 4];   // lin_W rows as 4x float4
    __shared__ float bl[OUT_CH];
    __shared__ float gb[HID];
    int t = threadIdx.x;
    if (t < HID * 4) Wl4[t] = ((const float4*)lin_W)[t];
    if (t >= 192 && t < 192 + OUT_CH) bl[t - 192] = lin_b[t - 192];
    if (t >= 208 && t < 208 + HID) gb[t - 208] = gat_bias[t - 208];
    __syncthreads();
    int n = blockIdx.x * blockDim.x + t;
    if (n >= N) return;

    const float4* a4 = (const float4*)(agg + (size_t)n * HID);
    float o[HID];
#pragma unroll
    for (int j = 0; j < 12; ++j) {
        float4 v = a4[j];
        o[4 * j + 0] = elu(v.x + gb[4 * j + 0]);
        o[4 * j + 1] = elu(v.y + gb[4 * j + 1]);
        o[4 * j + 2] = elu(v.z + gb[4 * j + 2]);
        o[4 * j + 3] = elu(v.w + gb[4 * j + 3]);
    }
    float z[OUT_CH];
#pragma unroll
    for (int oc = 0; oc < OUT_CH; ++oc) z[oc] = bl[oc];
#pragma unroll
    for (int k = 0; k < HID; ++k) {
        float ov = o[k];
#pragma unroll
        for (int q = 0; q < 4; ++q) {
            float4 w = Wl4[k * 4 + q];
            z[q * 4 + 0] += ov * w.x;
            z[q * 4 + 1] += ov * w.y;
            z[q * 4 + 2] += ov * w.z;
            z[q * 4 + 3] += ov * w.w;
        }
    }
    float mx = z[0];
#pragma unroll
    for (int oc = 1; oc < OUT_CH; ++oc) mx = fmaxf(mx, z[oc]);
    float sum = 0.f;
#pragma unroll
    for (int oc = 0; oc < OUT_CH; ++oc) sum += expf(z[oc] - mx);
    float lse = mx + logf(sum);
    float4* o4 = (float4*)(out + (size_t)n * OUT_CH);
#pragma unroll
    for (int q = 0; q < 4; ++q)
        o4[q] = make_float4(z[q * 4 + 0] - lse, z[q * 4 + 1] - lse,
                            z[q * 4 + 2] - lse, z[q * 4 + 3] - lse);
}

extern "C" void kernel_launch(void* const* d_in, const int* in_sizes, int n_in,
                              void* d_out, int out_size, void* d_ws, size_t ws_size,
                              hipStream_t stream) {
    const float* x = (const float*)d_in[0];
    const void* edge_index = d_in[1];
    const float* W = (const float*)d_in[2];
    const float* att_src = (const float*)d_in[3];
    const float* att_dst = (const float*)d_in[4];
    const float* gat_bias = (const float*)d_in[5];
    const float* lin_W = (const float*)d_in[6];
    const float* lin_b = (const float*)d_in[7];
    float* out = (float*)d_out;

    const int N = in_sizes[0] / IN_CH;
    const int E = in_sizes[1] / 2;

    float* ws = (float*)d_ws;
    float* h = ws;                         // N*48
    float* a_src = h + (size_t)N * HID;    // N
    float* a_dst = a_src + N;              // N
    float* m = a_dst + N;                  // N
    float* denom = m + N;                  // N
    float* agg = denom + N;                // N*48
    unsigned* maxenc = (unsigned*)(agg + (size_t)N * HID);  // N
    int* flag = (int*)(maxenc + N);        // 1

    const int nodeBlocks = (N + 255) / 256;
    const int edgeBlocks = (E + 255) / 256;

    k_detect<<<1, 64, 0, stream>>>((const unsigned*)edge_index, flag);
    k_xw<<<(N + BLK_NODES - 1) / BLK_NODES, 256, 0, stream>>>(x, W, h, N);
    k_attn_node<<<nodeBlocks, 256, 0, stream>>>(h, att_src, att_dst, a_src, a_dst, maxenc, N);
    k_edge_max<<<edgeBlocks, 256, 0, stream>>>(edge_index, flag, a_src, a_dst, maxenc, E);
    k_node_denom<<<nodeBlocks, 256, 0, stream>>>(a_src, a_dst, maxenc, m, denom, N);
    k_edge_sum<<<edgeBlocks, 256, 0, stream>>>(edge_index, flag, a_src, a_dst, m, denom, E);
    k_agg_init<<<nodeBlocks, 256, 0, stream>>>(h, a_src, a_dst, m, denom, agg, N);
    k_edge_agg<<<(int)(((size_t)E * 12 + 255) / 256), 256, 0, stream>>>(
        edge_index, flag, a_src, a_dst, m, denom, h, agg, E);
    k_out<<<nodeBlocks, 256, 0, stream>>>(agg, gat_bias, lin_W, lin_b, out, N);
}

// Round 2
// 430.655 us; speedup vs baseline: 2.8246x; 2.8246x over previous
//
#include <hip/hip_runtime.h>

#define IN_CH 128
#define HID 48
#define OUT_CH 16
#define NEG_SLOPE 0.2f
#define SCAN_ELEMS 2048   // per block: 256 threads x 8

__device__ __forceinline__ float leaky(float x) { return x >= 0.f ? x : NEG_SLOPE * x; }
__device__ __forceinline__ float elu(float x) { return x > 0.f ? x : expf(x) - 1.f; }

// Edge index fetch that tolerates either int32 or int64 storage.
__device__ __forceinline__ void load_edge(const void* ei, int E, int is64, int e,
                                          int& s, int& d) {
    if (is64) {
        const long long* p = (const long long*)ei;
        s = (int)p[e];
        d = (int)p[(size_t)E + e];
    } else {
        const int* p = (const int*)ei;
        s = p[e];
        d = p[(size_t)E + e];
    }
}

__global__ void k_detect(const unsigned* __restrict__ ei, int* __restrict__ flag) {
    if (threadIdx.x == 0 && blockIdx.x == 0) {
        unsigned s = 0;
        for (int i = 1; i < 128; i += 2) s |= ei[i];
        *flag = (s == 0) ? 1 : 0;
    }
}

// K1: h = x @ W. Block handles 256 nodes; thread: 4 nodes x 12 k register tile.
#define BLK_NODES 256
__global__ __launch_bounds__(256, 2) void k_xw(const float* __restrict__ x,
                                               const float* __restrict__ W,
                                               float* __restrict__ h, int N) {
    __shared__ float Wl[IN_CH * HID];
    __shared__ float xl[BLK_NODES * 33];
    const int t = threadIdx.x;
    for (int i = t; i < IN_CH * HID / 4; i += 256)
        ((float4*)Wl)[i] = ((const float4*)W)[i];
    const int n0 = blockIdx.x * BLK_NODES;
    const int kq = t & 3;
    const int ng = t >> 2;
    const int k0 = kq * 12;

    float acc[4][12];
#pragma unroll
    for (int i = 0; i < 4; ++i)
#pragma unroll
        for (int j = 0; j < 12; ++j) acc[i][j] = 0.f;

    for (int c0 = 0; c0 < IN_CH; c0 += 32) {
        __syncthreads();
#pragma unroll
        for (int p = 0; p < 8; ++p) {
            int id = t + p * 256;
            int row = id >> 3;
            int seg = id & 7;
            int n = n0 + row;
            float4 v = make_float4(0.f, 0.f, 0.f, 0.f);
            if (n < N) v = ((const float4*)(x + (size_t)n * IN_CH + c0))[seg];
            float* dst = &xl[row * 33 + seg * 4];
            dst[0] = v.x; dst[1] = v.y; dst[2] = v.z; dst[3] = v.w;
        }
        __syncthreads();
#pragma unroll 8
        for (int cc = 0; cc < 32; ++cc) {
            int c = c0 + cc;
            float xv[4];
#pragma unroll
            for (int i = 0; i < 4; ++i) xv[i] = xl[(ng * 4 + i) * 33 + cc];
            const float* wr = &Wl[c * HID + k0];
#pragma unroll
            for (int j = 0; j < 12; ++j) {
                float wv = wr[j];
#pragma unroll
                for (int i = 0; i < 4; ++i) acc[i][j] += xv[i] * wv;
            }
        }
    }
#pragma unroll
    for (int i = 0; i < 4; ++i) {
        int n = n0 + ng * 4 + i;
        if (n < N) {
#pragma unroll
            for (int j = 0; j < 12; j += 4) {
                float4 v = make_float4(acc[i][j], acc[i][j + 1], acc[i][j + 2], acc[i][j + 3]);
                *((float4*)(h + (size_t)n * HID + k0 + j)) = v;
            }
        }
    }
}

// K2: per-node attention terms; also zero the degree array.
__global__ __launch_bounds__(256) void k_attn_node(const float* __restrict__ h,
                                                   const float* __restrict__ att_src,
                                                   const float* __restrict__ att_dst,
                                                   float* __restrict__ a_src,
                                                   float* __restrict__ a_dst,
                                                   int* __restrict__ deg, int N) {
    int n = blockIdx.x * blockDim.x + threadIdx.x;
    if (n >= N) return;
    const float4* h4 = (const float4*)(h + (size_t)n * HID);
    float as = 0.f, ad = 0.f;
#pragma unroll
    for (int j = 0; j < 12; ++j) {
        float4 v = h4[j];
        as += v.x * att_src[4 * j + 0] + v.y * att_src[4 * j + 1] +
              v.z * att_src[4 * j + 2] + v.w * att_src[4 * j + 3];
        ad += v.x * att_dst[4 * j + 0] + v.y * att_dst[4 * j + 1] +
              v.z * att_dst[4 * j + 2] + v.w * att_dst[4 * j + 3];
    }
    a_src[n] = as;
    a_dst[n] = ad;
    deg[n] = 0;
}

// K3: in-degree count
__global__ __launch_bounds__(256) void k_count(const void* __restrict__ ei,
                                               const int* __restrict__ flag,
                                               int* __restrict__ deg, int E) {
    int e = blockIdx.x * blockDim.x + threadIdx.x;
    if (e >= E) return;
    int is64 = *flag;
    int s, d;
    load_edge(ei, E, is64, e, s, d);
    atomicAdd(&deg[d], 1);
}

// K4a: per-block exclusive scan of deg -> rowptr (local), block sums -> bsum
__global__ __launch_bounds__(256) void k_scan_block(const int* __restrict__ deg,
                                                    int* __restrict__ rowptr,
                                                    int* __restrict__ bsum, int N) {
    __shared__ int sm[256];
    const int t = threadIdx.x;
    const int base = blockIdx.x * SCAN_ELEMS + t * 8;
    int v[8];
    int s = 0;
#pragma unroll
    for (int i = 0; i < 8; ++i) {
        v[i] = (base + i < N) ? deg[base + i] : 0;
        s += v[i];
    }
    sm[t] = s;
    __syncthreads();
    // Hillis-Steele inclusive scan over 256 thread sums
    for (int off = 1; off < 256; off <<= 1) {
        int y = (t >= off) ? sm[t - off] : 0;
        __syncthreads();
        sm[t] += y;
        __syncthreads();
    }
    int run = sm[t] - s;  // exclusive prefix for this thread's first element
#pragma unroll
    for (int i = 0; i < 8; ++i) {
        if (base + i < N) rowptr[base + i] = run;
        run += v[i];
    }
    if (t == 255) bsum[blockIdx.x] = sm[255];
}

// K4b: scan the block sums in place (exclusive)
__global__ void k_scan_partials(int* __restrict__ bsum, int nb) {
    if (threadIdx.x == 0 && blockIdx.x == 0) {
        int run = 0;
        for (int b = 0; b < nb; ++b) {
            int t = bsum[b];
            bsum[b] = run;
            run += t;
        }
    }
}

// K4c: add block offsets; init cursor; set rowptr[N]=E
__global__ __launch_bounds__(256) void k_scan_add(int* __restrict__ rowptr,
                                                  const int* __restrict__ bsum,
                                                  int* __restrict__ cursor, int N, int E) {
    int i = blockIdx.x * blockDim.x + threadIdx.x;
    if (i == 0) rowptr[N] = E;
    if (i >= N) return;
    int r = rowptr[i] + bsum[i / SCAN_ELEMS];
    rowptr[i] = r;
    cursor[i] = r;
}

// K5: scatter edges into CSR; store src index and full logit
__global__ __launch_bounds__(256) void k_scatter(const void* __restrict__ ei,
                                                 const int* __restrict__ flag,
                                                 const float* __restrict__ a_src,
                                                 const float* __restrict__ a_dst,
                                                 int* __restrict__ cursor,
                                                 int* __restrict__ edge_src,
                                                 float* __restrict__ edge_logit, int E) {
    int e = blockIdx.x * blockDim.x + threadIdx.x;
    if (e >= E) return;
    int is64 = *flag;
    int s, d;
    load_edge(ei, E, is64, e, s, d);
    int pos = atomicAdd(&cursor[d], 1);
    edge_src[pos] = s;
    edge_logit[pos] = leaky(a_src[s] + a_dst[d]);
}

// K6: fused per-node softmax + aggregation + elu + linear + log_softmax.
// One wave (64 lanes) per node; 4 waves per block.
__global__ __launch_bounds__(256) void k_gat_node(const int* __restrict__ rowptr,
                                                  const int* __restrict__ edge_src,
                                                  const float* __restrict__ edge_logit,
                                                  const float* __restrict__ a_src,
                                                  const float* __restrict__ a_dst,
                                                  const float* __restrict__ h,
                                                  const float* __restrict__ gat_bias,
                                                  const float* __restrict__ lin_W,
                                                  const float* __restrict__ lin_b,
                                                  float* __restrict__ out, int N) {
    __shared__ float Wl[HID * OUT_CH];
    __shared__ float lb[OUT_CH];
    __shared__ float gb[HID];
    __shared__ float o_sm[4][HID];
    const int t = threadIdx.x;
    for (int i = t; i < HID * OUT_CH; i += 256) Wl[i] = lin_W[i];
    if (t < OUT_CH) lb[t] = lin_b[t];
    if (t >= 64 && t < 64 + HID) gb[t - 64] = gat_bias[t - 64];
    __syncthreads();

    const int wv = t >> 6;
    const int lane = t & 63;
    const int n = blockIdx.x * 4 + wv;
    const bool active = n < N;

    float acc = 0.f;
    float lse_out = 0.f;
    if (active) {
        const int base = rowptr[n];
        const int deg = rowptr[n + 1] - base;
        const float self_l = leaky(a_src[n] + a_dst[n]);

        // pass A1: max
        float m = self_l;
        for (int j0 = 0; j0 < deg; j0 += 64) {
            float l = -1e30f;
            if (j0 + lane < deg) l = edge_logit[base + j0 + lane];
#pragma unroll
            for (int off = 32; off; off >>= 1) l = fmaxf(l, __shfl_xor(l, off));
            m = fmaxf(m, l);
        }
        // pass A2: sum exp
        float ssum = expf(self_l - m);
        for (int j0 = 0; j0 < deg; j0 += 64) {
            float ev = 0.f;
            if (j0 + lane < deg) ev = expf(edge_logit[base + j0 + lane] - m);
#pragma unroll
            for (int off = 32; off; off >>= 1) ev += __shfl_xor(ev, off);
            ssum += ev;
        }
        const float inv = 1.f / ssum;

        // pass B: weighted gather-aggregate; lanes 0..47 hold channels
        const float alpha_self = expf(self_l - m) * inv;
        if (lane < HID) acc = alpha_self * h[(size_t)n * HID + lane];
        for (int j = 0; j < deg; ++j) {
            float lj = edge_logit[base + j];
            int sj = edge_src[base + j];
            float alpha = expf(lj - m) * inv;
            if (lane < HID) acc += alpha * h[(size_t)sj * HID + lane];
        }
        if (lane < HID) o_sm[wv][lane] = elu(acc + gb[lane]);
    }
    __syncthreads();

    if (active && lane < OUT_CH) {
        float z = lb[lane];
        const float* o = o_sm[wv];
#pragma unroll
        for (int k = 0; k < HID; ++k) z += o[k] * Wl[k * OUT_CH + lane];
        // log_softmax over 16 lanes
        float mx = z;
#pragma unroll
        for (int off = 8; off; off >>= 1) mx = fmaxf(mx, __shfl_xor(mx, off, 16));
        float ev = expf(z - mx);
#pragma unroll
        for (int off = 8; off; off >>= 1) ev += __shfl_xor(ev, off, 16);
        lse_out = mx + logf(ev);
        out[(size_t)n * OUT_CH + lane] = z - lse_out;
    }
}

extern "C" void kernel_launch(void* const* d_in, const int* in_sizes, int n_in,
                              void* d_out, int out_size, void* d_ws, size_t ws_size,
                              hipStream_t stream) {
    const float* x = (const float*)d_in[0];
    const void* edge_index = d_in[1];
    const float* W = (const float*)d_in[2];
    const float* att_src = (const float*)d_in[3];
    const float* att_dst = (const float*)d_in[4];
    const float* gat_bias = (const float*)d_in[5];
    const float* lin_W = (const float*)d_in[6];
    const float* lin_b = (const float*)d_in[7];
    float* out = (float*)d_out;

    const int N = in_sizes[0] / IN_CH;
    const int E = in_sizes[1] / 2;

    float* ws = (float*)d_ws;
    float* h = ws;                               // N*48
    float* a_src = h + (size_t)N * HID;          // N
    float* a_dst = a_src + N;                    // N
    float* edge_logit = a_dst + N;               // E
    int* rowptr = (int*)(edge_logit + E);        // N+1
    int* deg = rowptr;                           // reused: deg lives in rowptr pre-scan? NO — need both
    int* cursor = rowptr + N + 1;                // N
    int* degbuf = cursor + N;                    // N
    int* edge_src = degbuf + N;                  // E
    int* bsum = edge_src + E;                    // 64
    int* flag = bsum + 64;                       // 1

    const int nodeBlocks = (N + 255) / 256;
    const int edgeBlocks = (E + 255) / 256;
    const int scanBlocks = (N + SCAN_ELEMS - 1) / SCAN_ELEMS;

    k_detect<<<1, 64, 0, stream>>>((const unsigned*)edge_index, flag);
    k_xw<<<(N + BLK_NODES - 1) / BLK_NODES, 256, 0, stream>>>(x, W, h, N);
    k_attn_node<<<nodeBlocks, 256, 0, stream>>>(h, att_src, att_dst, a_src, a_dst, degbuf, N);
    k_count<<<edgeBlocks, 256, 0, stream>>>(edge_index, flag, degbuf, E);
    k_scan_block<<<scanBlocks, 256, 0, stream>>>(degbuf, rowptr, bsum, N);
    k_scan_partials<<<1, 64, 0, stream>>>(bsum, scanBlocks);
    k_scan_add<<<nodeBlocks, 256, 0, stream>>>(rowptr, bsum, cursor, N, E);
    k_scatter<<<edgeBlocks, 256, 0, stream>>>(edge_index, flag, a_src, a_dst, cursor,
                                              edge_src, edge_logit, E);
    k_gat_node<<<(N + 3) / 4, 256, 0, stream>>>(rowptr, edge_src, edge_logit, a_src, a_dst,
                                                h, gat_bias, lin_W, lin_b, out, N);
}

// Round 3
// 314.956 us; speedup vs baseline: 3.8622x; 1.3673x over previous
//
#include <hip/hip_runtime.h>

#define IN_CH 128
#define HID 48
#define OUT_CH 16
#define NEG_SLOPE 0.2f
#define SCAN_ELEMS 2048   // per block: 256 threads x 8

__device__ __forceinline__ float leaky(float x) { return x >= 0.f ? x : NEG_SLOPE * x; }
__device__ __forceinline__ float elu(float x) { return x > 0.f ? x : __expf(x) - 1.f; }

// Edge index fetch that tolerates either int32 or int64 storage.
__device__ __forceinline__ void load_edge(const void* ei, int E, int is64, int e,
                                          int& s, int& d) {
    if (is64) {
        const long long* p = (const long long*)ei;
        s = (int)p[e];
        d = (int)p[(size_t)E + e];
    } else {
        const int* p = (const int*)ei;
        s = p[e];
        d = p[(size_t)E + e];
    }
}

__global__ void k_detect(const unsigned* __restrict__ ei, int* __restrict__ flag) {
    if (threadIdx.x == 0 && blockIdx.x == 0) {
        unsigned s = 0;
        for (int i = 1; i < 128; i += 2) s |= ei[i];
        *flag = (s == 0) ? 1 : 0;
    }
}

// K1: h = x @ W. Block handles 256 nodes; thread: 4 nodes x 12 k register tile.
#define BLK_NODES 256
__global__ __launch_bounds__(256, 2) void k_xw(const float* __restrict__ x,
                                               const float* __restrict__ W,
                                               float* __restrict__ h, int N) {
    __shared__ float Wl[IN_CH * HID];
    __shared__ float xl[BLK_NODES * 33];
    const int t = threadIdx.x;
    for (int i = t; i < IN_CH * HID / 4; i += 256)
        ((float4*)Wl)[i] = ((const float4*)W)[i];
    const int n0 = blockIdx.x * BLK_NODES;
    const int kq = t & 3;
    const int ng = t >> 2;
    const int k0 = kq * 12;

    float acc[4][12];
#pragma unroll
    for (int i = 0; i < 4; ++i)
#pragma unroll
        for (int j = 0; j < 12; ++j) acc[i][j] = 0.f;

    for (int c0 = 0; c0 < IN_CH; c0 += 32) {
        __syncthreads();
#pragma unroll
        for (int p = 0; p < 8; ++p) {
            int id = t + p * 256;
            int row = id >> 3;
            int seg = id & 7;
            int n = n0 + row;
            float4 v = make_float4(0.f, 0.f, 0.f, 0.f);
            if (n < N) v = ((const float4*)(x + (size_t)n * IN_CH + c0))[seg];
            float* dst = &xl[row * 33 + seg * 4];
            dst[0] = v.x; dst[1] = v.y; dst[2] = v.z; dst[3] = v.w;
        }
        __syncthreads();
#pragma unroll 8
        for (int cc = 0; cc < 32; ++cc) {
            int c = c0 + cc;
            float xv[4];
#pragma unroll
            for (int i = 0; i < 4; ++i) xv[i] = xl[(ng * 4 + i) * 33 + cc];
            const float* wr = &Wl[c * HID + k0];
#pragma unroll
            for (int j = 0; j < 12; ++j) {
                float wv = wr[j];
#pragma unroll
                for (int i = 0; i < 4; ++i) acc[i][j] += xv[i] * wv;
            }
        }
    }
#pragma unroll
    for (int i = 0; i < 4; ++i) {
        int n = n0 + ng * 4 + i;
        if (n < N) {
#pragma unroll
            for (int j = 0; j < 12; j += 4) {
                float4 v = make_float4(acc[i][j], acc[i][j + 1], acc[i][j + 2], acc[i][j + 3]);
                *((float4*)(h + (size_t)n * HID + k0 + j)) = v;
            }
        }
    }
}

// K2: per-node attention terms; also zero the degree array.
__global__ __launch_bounds__(256) void k_attn_node(const float* __restrict__ h,
                                                   const float* __restrict__ att_src,
                                                   const float* __restrict__ att_dst,
                                                   float* __restrict__ a_src,
                                                   float* __restrict__ a_dst,
                                                   int* __restrict__ deg, int N) {
    int n = blockIdx.x * blockDim.x + threadIdx.x;
    if (n >= N) return;
    const float4* h4 = (const float4*)(h + (size_t)n * HID);
    float as = 0.f, ad = 0.f;
#pragma unroll
    for (int j = 0; j < 12; ++j) {
        float4 v = h4[j];
        as += v.x * att_src[4 * j + 0] + v.y * att_src[4 * j + 1] +
              v.z * att_src[4 * j + 2] + v.w * att_src[4 * j + 3];
        ad += v.x * att_dst[4 * j + 0] + v.y * att_dst[4 * j + 1] +
              v.z * att_dst[4 * j + 2] + v.w * att_dst[4 * j + 3];
    }
    a_src[n] = as;
    a_dst[n] = ad;
    deg[n] = 0;
}

// K3: in-degree count
__global__ __launch_bounds__(256) void k_count(const void* __restrict__ ei,
                                               const int* __restrict__ flag,
                                               int* __restrict__ deg, int E) {
    int e = blockIdx.x * blockDim.x + threadIdx.x;
    if (e >= E) return;
    int is64 = *flag;
    int s, d;
    load_edge(ei, E, is64, e, s, d);
    atomicAdd(&deg[d], 1);
}

// K4a: per-block exclusive scan of deg -> rowptr (local), block sums -> bsum
__global__ __launch_bounds__(256) void k_scan_block(const int* __restrict__ deg,
                                                    int* __restrict__ rowptr,
                                                    int* __restrict__ bsum, int N) {
    __shared__ int sm[256];
    const int t = threadIdx.x;
    const int base = blockIdx.x * SCAN_ELEMS + t * 8;
    int v[8];
    int s = 0;
#pragma unroll
    for (int i = 0; i < 8; ++i) {
        v[i] = (base + i < N) ? deg[base + i] : 0;
        s += v[i];
    }
    sm[t] = s;
    __syncthreads();
    for (int off = 1; off < 256; off <<= 1) {
        int y = (t >= off) ? sm[t - off] : 0;
        __syncthreads();
        sm[t] += y;
        __syncthreads();
    }
    int run = sm[t] - s;
#pragma unroll
    for (int i = 0; i < 8; ++i) {
        if (base + i < N) rowptr[base + i] = run;
        run += v[i];
    }
    if (t == 255) bsum[blockIdx.x] = sm[255];
}

// K4b: scan the block sums in place (exclusive)
__global__ void k_scan_partials(int* __restrict__ bsum, int nb) {
    if (threadIdx.x == 0 && blockIdx.x == 0) {
        int run = 0;
        for (int b = 0; b < nb; ++b) {
            int t = bsum[b];
            bsum[b] = run;
            run += t;
        }
    }
}

// K4c: add block offsets; init cursor; set rowptr[N]=E
__global__ __launch_bounds__(256) void k_scan_add(int* __restrict__ rowptr,
                                                  const int* __restrict__ bsum,
                                                  int* __restrict__ cursor, int N, int E) {
    int i = blockIdx.x * blockDim.x + threadIdx.x;
    if (i == 0) rowptr[N] = E;
    if (i >= N) return;
    int r = rowptr[i] + bsum[i / SCAN_ELEMS];
    rowptr[i] = r;
    cursor[i] = r;
}

// K5: scatter edges into CSR; store src index and full logit
__global__ __launch_bounds__(256) void k_scatter(const void* __restrict__ ei,
                                                 const int* __restrict__ flag,
                                                 const float* __restrict__ a_src,
                                                 const float* __restrict__ a_dst,
                                                 int* __restrict__ cursor,
                                                 int* __restrict__ edge_src,
                                                 float* __restrict__ edge_logit, int E) {
    int e = blockIdx.x * blockDim.x + threadIdx.x;
    if (e >= E) return;
    int is64 = *flag;
    int s, d;
    load_edge(ei, E, is64, e, s, d);
    int pos = atomicAdd(&cursor[d], 1);
    edge_src[pos] = s;
    edge_logit[pos] = leaky(a_src[s] + a_dst[d]);
}

// K6: fused per-node softmax + aggregation + elu + linear + log_softmax.
// One wave per node, 4 waves/block. Wave layout: 4 edge-slots x 16 channels,
// each lane owns channels c, c+16, c+32 (3 regs). Unnormalized accumulation
// with ev = exp(l - m); scale by 1/sum at the end.
__global__ __launch_bounds__(256) void k_gat_node(const int* __restrict__ rowptr,
                                                  const int* __restrict__ edge_src,
                                                  const float* __restrict__ edge_logit,
                                                  const float* __restrict__ a_src,
                                                  const float* __restrict__ a_dst,
                                                  const float* __restrict__ h,
                                                  const float* __restrict__ gat_bias,
                                                  const float* __restrict__ lin_W,
                                                  const float* __restrict__ lin_b,
                                                  float* __restrict__ out, int N) {
    __shared__ float Wl[HID * OUT_CH];
    __shared__ float lb[OUT_CH];
    __shared__ float gb[HID];
    __shared__ float o_sm[4][HID];
    const int t = threadIdx.x;
    for (int i = t; i < HID * OUT_CH; i += 256) Wl[i] = lin_W[i];
    if (t < OUT_CH) lb[t] = lin_b[t];
    if (t >= 64 && t < 64 + HID) gb[t - 64] = gat_bias[t - 64];
    __syncthreads();

    const int wv = t >> 6;
    const int lane = t & 63;
    const int slot = lane >> 4;   // 0..3
    const int c = lane & 15;      // 0..15
    const int n = blockIdx.x * 4 + wv;
    const bool active = n < N;

    if (active) {
        const int base = rowptr[n];
        const int deg = rowptr[n + 1] - base;
        const float self_l = leaky(a_src[n] + a_dst[n]);

        // pass 1: running max over all edge logits (lane-parallel)
        float m = self_l;
        for (int j0 = 0; j0 < deg; j0 += 64) {
            float l = (j0 + lane < deg) ? edge_logit[base + j0 + lane] : -1e30f;
#pragma unroll
            for (int off = 32; off; off >>= 1) l = fmaxf(l, __shfl_xor(l, off));
            m = fmaxf(m, l);
        }

        const float ev_self = __expf(self_l - m);
        const float* hn = h + (size_t)n * HID;
        float acc0 = 0.f, acc1 = 0.f, acc2 = 0.f;
        if (slot == 0) {
            acc0 = ev_self * hn[c];
            acc1 = ev_self * hn[c + 16];
            acc2 = ev_self * hn[c + 32];
        }
        float evsum = 0.f;   // per-slot-group partial (identical within a group)
#pragma unroll 2
        for (int j = slot; j < deg; j += 4) {
            float lj = edge_logit[base + j];
            int sj = edge_src[base + j];
            float ev = __expf(lj - m);
            evsum += ev;
            const float* hp = h + (size_t)sj * HID;
            acc0 += ev * hp[c];
            acc1 += ev * hp[c + 16];
            acc2 += ev * hp[c + 32];
        }
        // cross-slot reduction: values are uniform within each 16-lane group,
        // so xor-16 and xor-32 sum the 4 distinct slot values exactly once.
        evsum += __shfl_xor(evsum, 16);
        evsum += __shfl_xor(evsum, 32);
        acc0 += __shfl_xor(acc0, 16);
        acc0 += __shfl_xor(acc0, 32);
        acc1 += __shfl_xor(acc1, 16);
        acc1 += __shfl_xor(acc1, 32);
        acc2 += __shfl_xor(acc2, 16);
        acc2 += __shfl_xor(acc2, 32);
        const float inv = 1.f / (evsum + ev_self);
        if (slot == 0) {
            o_sm[wv][c] = elu(acc0 * inv + gb[c]);
            o_sm[wv][c + 16] = elu(acc1 * inv + gb[c + 16]);
            o_sm[wv][c + 32] = elu(acc2 * inv + gb[c + 32]);
        }
    }
    __syncthreads();

    if (active && lane < OUT_CH) {
        float z = lb[lane];
        const float* o = o_sm[wv];
#pragma unroll
        for (int k = 0; k < HID; ++k) z += o[k] * Wl[k * OUT_CH + lane];
        float mx = z;
#pragma unroll
        for (int off = 8; off; off >>= 1) mx = fmaxf(mx, __shfl_xor(mx, off, 16));
        float ev = __expf(z - mx);
#pragma unroll
        for (int off = 8; off; off >>= 1) ev += __shfl_xor(ev, off, 16);
        float lse = mx + __logf(ev);
        out[(size_t)n * OUT_CH + lane] = z - lse;
    }
}

extern "C" void kernel_launch(void* const* d_in, const int* in_sizes, int n_in,
                              void* d_out, int out_size, void* d_ws, size_t ws_size,
                              hipStream_t stream) {
    const float* x = (const float*)d_in[0];
    const void* edge_index = d_in[1];
    const float* W = (const float*)d_in[2];
    const float* att_src = (const float*)d_in[3];
    const float* att_dst = (const float*)d_in[4];
    const float* gat_bias = (const float*)d_in[5];
    const float* lin_W = (const float*)d_in[6];
    const float* lin_b = (const float*)d_in[7];
    float* out = (float*)d_out;

    const int N = in_sizes[0] / IN_CH;
    const int E = in_sizes[1] / 2;

    float* ws = (float*)d_ws;
    float* h = ws;                               // N*48
    float* a_src = h + (size_t)N * HID;          // N
    float* a_dst = a_src + N;                    // N
    float* edge_logit = a_dst + N;               // E
    int* rowptr = (int*)(edge_logit + E);        // N+1
    int* cursor = rowptr + N + 1;                // N
    int* degbuf = cursor + N;                    // N
    int* edge_src = degbuf + N;                  // E
    int* bsum = edge_src + E;                    // scanBlocks
    int* flag = bsum + 64;                       // 1

    const int nodeBlocks = (N + 255) / 256;
    const int edgeBlocks = (E + 255) / 256;
    const int scanBlocks = (N + SCAN_ELEMS - 1) / SCAN_ELEMS;

    k_detect<<<1, 64, 0, stream>>>((const unsigned*)edge_index, flag);
    k_xw<<<(N + BLK_NODES - 1) / BLK_NODES, 256, 0, stream>>>(x, W, h, N);
    k_attn_node<<<nodeBlocks, 256, 0, stream>>>(h, att_src, att_dst, a_src, a_dst, degbuf, N);
    k_count<<<edgeBlocks, 256, 0, stream>>>(edge_index, flag, degbuf, E);
    k_scan_block<<<scanBlocks, 256, 0, stream>>>(degbuf, rowptr, bsum, N);
    k_scan_partials<<<1, 64, 0, stream>>>(bsum, scanBlocks);
    k_scan_add<<<nodeBlocks, 256, 0, stream>>>(rowptr, bsum, cursor, N, E);
    k_scatter<<<edgeBlocks, 256, 0, stream>>>(edge_index, flag, a_src, a_dst, cursor,
                                              edge_src, edge_logit, E);
    k_gat_node<<<(N + 3) / 4, 256, 0, stream>>>(rowptr, edge_src, edge_logit, a_src, a_dst,
                                                h, gat_bias, lin_W, lin_b, out, N);
}

// Round 4
// 259.838 us; speedup vs baseline: 4.6815x; 1.2121x over previous
//
#include <hip/hip_runtime.h>

#define IN_CH 128
#define HID 48
#define OUT_CH 16
#define NEG_SLOPE 0.2f
#define SCAN_ELEMS 2048   // per block: 256 threads x 8

__device__ __forceinline__ float leaky(float x) { return x >= 0.f ? x : NEG_SLOPE * x; }
__device__ __forceinline__ float elu(float x) { return x > 0.f ? x : __expf(x) - 1.f; }

// Edge index fetch that tolerates either int32 or int64 storage.
__device__ __forceinline__ void load_edge(const void* ei, int E, int is64, int e,
                                          int& s, int& d) {
    if (is64) {
        const long long* p = (const long long*)ei;
        s = (int)p[e];
        d = (int)p[(size_t)E + e];
    } else {
        const int* p = (const int*)ei;
        s = p[e];
        d = p[(size_t)E + e];
    }
}

__global__ void k_detect(const unsigned* __restrict__ ei, int* __restrict__ flag) {
    if (threadIdx.x == 0 && blockIdx.x == 0) {
        unsigned s = 0;
        for (int i = 1; i < 128; i += 2) s |= ei[i];
        *flag = (s == 0) ? 1 : 0;
    }
}

// K1: h = x @ W fused with a_src/a_dst computation and deg zeroing.
// Block = 256 nodes; thread: 4 nodes x 12 k register tile.
#define BLK_NODES 256
__global__ __launch_bounds__(256, 2) void k_xw(const float* __restrict__ x,
                                               const float* __restrict__ W,
                                               const float* __restrict__ att_src,
                                               const float* __restrict__ att_dst,
                                               float* __restrict__ h,
                                               float* __restrict__ a_src,
                                               float* __restrict__ a_dst,
                                               int* __restrict__ deg, int N) {
    __shared__ float Wl[IN_CH * HID];
    __shared__ float xl[BLK_NODES * 33];
    const int t = threadIdx.x;
    for (int i = t; i < IN_CH * HID / 4; i += 256)
        ((float4*)Wl)[i] = ((const float4*)W)[i];
    const int n0 = blockIdx.x * BLK_NODES;
    const int kq = t & 3;
    const int ng = t >> 2;
    const int k0 = kq * 12;

    float acc[4][12];
#pragma unroll
    for (int i = 0; i < 4; ++i)
#pragma unroll
        for (int j = 0; j < 12; ++j) acc[i][j] = 0.f;

    for (int c0 = 0; c0 < IN_CH; c0 += 32) {
        __syncthreads();
#pragma unroll
        for (int p = 0; p < 8; ++p) {
            int id = t + p * 256;
            int row = id >> 3;
            int seg = id & 7;
            int n = n0 + row;
            float4 v = make_float4(0.f, 0.f, 0.f, 0.f);
            if (n < N) v = ((const float4*)(x + (size_t)n * IN_CH + c0))[seg];
            float* dst = &xl[row * 33 + seg * 4];
            dst[0] = v.x; dst[1] = v.y; dst[2] = v.z; dst[3] = v.w;
        }
        __syncthreads();
#pragma unroll 8
        for (int cc = 0; cc < 32; ++cc) {
            int c = c0 + cc;
            float xv[4];
#pragma unroll
            for (int i = 0; i < 4; ++i) xv[i] = xl[(ng * 4 + i) * 33 + cc];
            const float* wr = &Wl[c * HID + k0];
#pragma unroll
            for (int j = 0; j < 12; ++j) {
                float wv = wr[j];
#pragma unroll
                for (int i = 0; i < 4; ++i) acc[i][j] += xv[i] * wv;
            }
        }
    }
#pragma unroll
    for (int i = 0; i < 4; ++i) {
        int n = n0 + ng * 4 + i;
        if (n < N) {
#pragma unroll
            for (int j = 0; j < 12; j += 4) {
                float4 v = make_float4(acc[i][j], acc[i][j + 1], acc[i][j + 2], acc[i][j + 3]);
                *((float4*)(h + (size_t)n * HID + k0 + j)) = v;
            }
        }
    }
    // fused attention terms: partial dot over this thread's 12 channels,
    // reduce across the 4 kq lanes (t^1, t^2 within the same node group).
    float as_[4], ad_[4];
#pragma unroll
    for (int i = 0; i < 4; ++i) {
        float s1 = 0.f, s2 = 0.f;
#pragma unroll
        for (int j = 0; j < 12; ++j) {
            float a = acc[i][j];
            s1 += a * att_src[k0 + j];
            s2 += a * att_dst[k0 + j];
        }
        s1 += __shfl_xor(s1, 1); s1 += __shfl_xor(s1, 2);
        s2 += __shfl_xor(s2, 1); s2 += __shfl_xor(s2, 2);
        as_[i] = s1; ad_[i] = s2;
    }
    if (kq == 0) {
#pragma unroll
        for (int i = 0; i < 4; ++i) {
            int n = n0 + ng * 4 + i;
            if (n < N) { a_src[n] = as_[i]; a_dst[n] = ad_[i]; }
        }
    }
    {
        int n = n0 + t;
        if (n < N) deg[n] = 0;
    }
}

// K3: in-degree count; atomic return value = edge's rank within its destination.
__global__ __launch_bounds__(256) void k_count(const void* __restrict__ ei,
                                               const int* __restrict__ flag,
                                               int* __restrict__ deg,
                                               int* __restrict__ rank, int E) {
    int e = blockIdx.x * blockDim.x + threadIdx.x;
    if (e >= E) return;
    int is64 = *flag;
    int s, d;
    load_edge(ei, E, is64, e, s, d);
    rank[e] = atomicAdd(&deg[d], 1);
}

// K4a: per-block exclusive scan of deg -> rowptr (local), block sums -> bsum
__global__ __launch_bounds__(256) void k_scan_block(const int* __restrict__ deg,
                                                    int* __restrict__ rowptr,
                                                    int* __restrict__ bsum, int N) {
    __shared__ int sm[256];
    const int t = threadIdx.x;
    const int base = blockIdx.x * SCAN_ELEMS + t * 8;
    int v[8];
    int s = 0;
#pragma unroll
    for (int i = 0; i < 8; ++i) {
        v[i] = (base + i < N) ? deg[base + i] : 0;
        s += v[i];
    }
    sm[t] = s;
    __syncthreads();
    for (int off = 1; off < 256; off <<= 1) {
        int y = (t >= off) ? sm[t - off] : 0;
        __syncthreads();
        sm[t] += y;
        __syncthreads();
    }
    int run = sm[t] - s;
#pragma unroll
    for (int i = 0; i < 8; ++i) {
        if (base + i < N) rowptr[base + i] = run;
        run += v[i];
    }
    if (t == 255) bsum[blockIdx.x] = sm[255];
}

// K4b: scan the block sums in place (exclusive)
__global__ void k_scan_partials(int* __restrict__ bsum, int nb) {
    if (threadIdx.x == 0 && blockIdx.x == 0) {
        int run = 0;
        for (int b = 0; b < nb; ++b) {
            int t = bsum[b];
            bsum[b] = run;
            run += t;
        }
    }
}

// K4c: add block offsets; set rowptr[N]=E
__global__ __launch_bounds__(256) void k_scan_add(int* __restrict__ rowptr,
                                                  const int* __restrict__ bsum, int N, int E) {
    int i = blockIdx.x * blockDim.x + threadIdx.x;
    if (i == 0) rowptr[N] = E;
    if (i >= N) return;
    rowptr[i] += bsum[i / SCAN_ELEMS];
}

// K5: scatter edges into CSR (no atomics): pos = rowptr[d] + rank[e].
// One packed 8B nontemporal store per edge: (src, exp(logit)).
__global__ __launch_bounds__(256) void k_scatter(const void* __restrict__ ei,
                                                 const int* __restrict__ flag,
                                                 const float* __restrict__ a_src,
                                                 const float* __restrict__ a_dst,
                                                 const int* __restrict__ rowptr,
                                                 const int* __restrict__ rank,
                                                 unsigned long long* __restrict__ packed,
                                                 int E) {
    int e = blockIdx.x * blockDim.x + threadIdx.x;
    if (e >= E) return;
    int is64 = *flag;
    int s, d;
    load_edge(ei, E, is64, e, s, d);
    int pos = rowptr[d] + rank[e];
    float l = leaky(a_src[s] + a_dst[d]);
    float ev = __expf(fminf(l, 50.f));
    unsigned long long u = ((unsigned long long)__float_as_uint(ev) << 32) | (unsigned)s;
    __builtin_nontemporal_store(u, packed + pos);
}

// K6: fused per-node aggregation + elu + linear + log_softmax. One wave per
// node, 4 waves/block; 4 edge-slots x 16 channels, 3 channels/lane.
// Unnormalized accumulation with precomputed ev; single pass, no max sweep.
__global__ __launch_bounds__(256) void k_gat_node(const int* __restrict__ rowptr,
                                                  const unsigned long long* __restrict__ packed,
                                                  const float* __restrict__ a_src,
                                                  const float* __restrict__ a_dst,
                                                  const float* __restrict__ h,
                                                  const float* __restrict__ gat_bias,
                                                  const float* __restrict__ lin_W,
                                                  const float* __restrict__ lin_b,
                                                  float* __restrict__ out, int N) {
    __shared__ float Wl[HID * OUT_CH];
    __shared__ float lb[OUT_CH];
    __shared__ float gb[HID];
    __shared__ float o_sm[4][HID];
    const int t = threadIdx.x;
    for (int i = t; i < HID * OUT_CH; i += 256) Wl[i] = lin_W[i];
    if (t < OUT_CH) lb[t] = lin_b[t];
    if (t >= 64 && t < 64 + HID) gb[t - 64] = gat_bias[t - 64];
    __syncthreads();

    const int wv = t >> 6;
    const int lane = t & 63;
    const int slot = lane >> 4;   // 0..3
    const int c = lane & 15;      // 0..15
    const int n = blockIdx.x * 4 + wv;
    const bool active = n < N;

    if (active) {
        const int base = rowptr[n];
        const int deg = rowptr[n + 1] - base;
        const float self_l = leaky(a_src[n] + a_dst[n]);
        const float ev_self = __expf(fminf(self_l, 50.f));

        const float* hn = h + (size_t)n * HID;
        float acc0 = 0.f, acc1 = 0.f, acc2 = 0.f;
        if (slot == 0) {
            acc0 = ev_self * hn[c];
            acc1 = ev_self * hn[c + 16];
            acc2 = ev_self * hn[c + 32];
        }
        float evsum = 0.f;   // per-slot-group partial (identical within group)
#pragma unroll 4
        for (int j = slot; j < deg; j += 4) {
            unsigned long long pr = packed[base + j];
            int sj = (int)(unsigned)pr;
            float ev = __uint_as_float((unsigned)(pr >> 32));
            evsum += ev;
            const float* hp = h + (size_t)sj * HID;
            acc0 += ev * hp[c];
            acc1 += ev * hp[c + 16];
            acc2 += ev * hp[c + 32];
        }
        // cross-slot reduction (values uniform within each 16-lane group)
        evsum += __shfl_xor(evsum, 16);
        evsum += __shfl_xor(evsum, 32);
        acc0 += __shfl_xor(acc0, 16);
        acc0 += __shfl_xor(acc0, 32);
        acc1 += __shfl_xor(acc1, 16);
        acc1 += __shfl_xor(acc1, 32);
        acc2 += __shfl_xor(acc2, 16);
        acc2 += __shfl_xor(acc2, 32);
        const float inv = 1.f / (evsum + ev_self);
        if (slot == 0) {
            o_sm[wv][c] = elu(acc0 * inv + gb[c]);
            o_sm[wv][c + 16] = elu(acc1 * inv + gb[c + 16]);
            o_sm[wv][c + 32] = elu(acc2 * inv + gb[c + 32]);
        }
    }
    __syncthreads();

    if (active && lane < OUT_CH) {
        float z = lb[lane];
        const float* o = o_sm[wv];
#pragma unroll
        for (int k = 0; k < HID; ++k) z += o[k] * Wl[k * OUT_CH + lane];
        float mx = z;
#pragma unroll
        for (int off = 8; off; off >>= 1) mx = fmaxf(mx, __shfl_xor(mx, off, 16));
        float ev = __expf(z - mx);
#pragma unroll
        for (int off = 8; off; off >>= 1) ev += __shfl_xor(ev, off, 16);
        float lse = mx + __logf(ev);
        out[(size_t)n * OUT_CH + lane] = z - lse;
    }
}

extern "C" void kernel_launch(void* const* d_in, const int* in_sizes, int n_in,
                              void* d_out, int out_size, void* d_ws, size_t ws_size,
                              hipStream_t stream) {
    const float* x = (const float*)d_in[0];
    const void* edge_index = d_in[1];
    const float* W = (const float*)d_in[2];
    const float* att_src = (const float*)d_in[3];
    const float* att_dst = (const float*)d_in[4];
    const float* gat_bias = (const float*)d_in[5];
    const float* lin_W = (const float*)d_in[6];
    const float* lin_b = (const float*)d_in[7];
    float* out = (float*)d_out;

    const int N = in_sizes[0] / IN_CH;
    const int E = in_sizes[1] / 2;

    float* ws = (float*)d_ws;
    float* h = ws;                               // N*48
    float* a_src = h + (size_t)N * HID;          // N
    float* a_dst = a_src + N;                    // N
    int* rank = (int*)(a_dst + N);               // E
    int* rowptr = rank + E;                      // N+1
    int* degbuf = rowptr + N + 1;                // N
    int* bsum = degbuf + N;                      // 64
    int* flag = bsum + 64;                       // 1
    size_t off = (size_t)((float*)(flag + 1) - ws);
    off = (off + 1) & ~(size_t)1;                // 8B align
    unsigned long long* packed = (unsigned long long*)(ws + off);  // E x 8B

    const int nodeBlocks = (N + 255) / 256;
    const int edgeBlocks = (E + 255) / 256;
    const int scanBlocks = (N + SCAN_ELEMS - 1) / SCAN_ELEMS;

    k_detect<<<1, 64, 0, stream>>>((const unsigned*)edge_index, flag);
    k_xw<<<(N + BLK_NODES - 1) / BLK_NODES, 256, 0, stream>>>(x, W, att_src, att_dst,
                                                              h, a_src, a_dst, degbuf, N);
    k_count<<<edgeBlocks, 256, 0, stream>>>(edge_index, flag, degbuf, rank, E);
    k_scan_block<<<scanBlocks, 256, 0, stream>>>(degbuf, rowptr, bsum, N);
    k_scan_partials<<<1, 64, 0, stream>>>(bsum, scanBlocks);
    k_scan_add<<<nodeBlocks, 256, 0, stream>>>(rowptr, bsum, N, E);
    k_scatter<<<edgeBlocks, 256, 0, stream>>>(edge_index, flag, a_src, a_dst, rowptr,
                                              rank, packed, E);
    k_gat_node<<<(N + 3) / 4, 256, 0, stream>>>(rowptr, packed, a_src, a_dst,
                                                h, gat_bias, lin_W, lin_b, out, N);
}

// Round 5
// 253.909 us; speedup vs baseline: 4.7908x; 1.0234x over previous
//
#include <hip/hip_runtime.h>
#include <hip/hip_fp16.h>

#define IN_CH 128
#define HID 48
#define OUT_CH 16
#define NEG_SLOPE 0.2f
#define SCAN_ELEMS 2048   // per block: 256 threads x 8

__device__ __forceinline__ float leaky(float x) { return x >= 0.f ? x : NEG_SLOPE * x; }
__device__ __forceinline__ float elu(float x) { return x > 0.f ? x : __expf(x) - 1.f; }

// Edge index fetch that tolerates either int32 or int64 storage.
__device__ __forceinline__ void load_edge(const void* ei, int E, int is64, int e,
                                          int& s, int& d) {
    if (is64) {
        const long long* p = (const long long*)ei;
        s = (int)p[e];
        d = (int)p[(size_t)E + e];
    } else {
        const int* p = (const int*)ei;
        s = p[e];
        d = p[(size_t)E + e];
    }
}

__global__ void k_detect(const unsigned* __restrict__ ei, int* __restrict__ flag) {
    if (threadIdx.x == 0 && blockIdx.x == 0) {
        unsigned s = 0;
        for (int i = 1; i < 128; i += 2) s |= ei[i];
        *flag = (s == 0) ? 1 : 0;
    }
}

// K1: h = x @ W (stored fp16) fused with a_src/a_dst computation and deg zeroing.
// Block = 256 nodes; thread: 4 nodes x 12 k register tile.
#define BLK_NODES 256
__global__ __launch_bounds__(256, 2) void k_xw(const float* __restrict__ x,
                                               const float* __restrict__ W,
                                               const float* __restrict__ att_src,
                                               const float* __restrict__ att_dst,
                                               __half* __restrict__ h2,
                                               float* __restrict__ a_src,
                                               float* __restrict__ a_dst,
                                               int* __restrict__ deg, int N) {
    __shared__ float Wl[IN_CH * HID];
    __shared__ float xl[BLK_NODES * 33];
    const int t = threadIdx.x;
    for (int i = t; i < IN_CH * HID / 4; i += 256)
        ((float4*)Wl)[i] = ((const float4*)W)[i];
    const int n0 = blockIdx.x * BLK_NODES;
    const int kq = t & 3;
    const int ng = t >> 2;
    const int k0 = kq * 12;

    float acc[4][12];
#pragma unroll
    for (int i = 0; i < 4; ++i)
#pragma unroll
        for (int j = 0; j < 12; ++j) acc[i][j] = 0.f;

    for (int c0 = 0; c0 < IN_CH; c0 += 32) {
        __syncthreads();
#pragma unroll
        for (int p = 0; p < 8; ++p) {
            int id = t + p * 256;
            int row = id >> 3;
            int seg = id & 7;
            int n = n0 + row;
            float4 v = make_float4(0.f, 0.f, 0.f, 0.f);
            if (n < N) v = ((const float4*)(x + (size_t)n * IN_CH + c0))[seg];
            float* dst = &xl[row * 33 + seg * 4];
            dst[0] = v.x; dst[1] = v.y; dst[2] = v.z; dst[3] = v.w;
        }
        __syncthreads();
#pragma unroll 8
        for (int cc = 0; cc < 32; ++cc) {
            int c = c0 + cc;
            float xv[4];
#pragma unroll
            for (int i = 0; i < 4; ++i) xv[i] = xl[(ng * 4 + i) * 33 + cc];
            const float* wr = &Wl[c * HID + k0];
#pragma unroll
            for (int j = 0; j < 12; ++j) {
                float wv = wr[j];
#pragma unroll
                for (int i = 0; i < 4; ++i) acc[i][j] += xv[i] * wv;
            }
        }
    }
#pragma unroll
    for (int i = 0; i < 4; ++i) {
        int n = n0 + ng * 4 + i;
        if (n < N) {
            uint* dst = (uint*)(h2 + (size_t)n * HID + k0);
#pragma unroll
            for (int j = 0; j < 6; ++j) {
                __half2 hv = __floats2half2_rn(acc[i][2 * j], acc[i][2 * j + 1]);
                dst[j] = *(const uint*)&hv;
            }
        }
    }
    // fused attention terms: partial dot over this thread's 12 channels,
    // reduce across the 4 kq lanes (t^1, t^2 within the same node group).
    float as_[4], ad_[4];
#pragma unroll
    for (int i = 0; i < 4; ++i) {
        float s1 = 0.f, s2 = 0.f;
#pragma unroll
        for (int j = 0; j < 12; ++j) {
            float a = acc[i][j];
            s1 += a * att_src[k0 + j];
            s2 += a * att_dst[k0 + j];
        }
        s1 += __shfl_xor(s1, 1); s1 += __shfl_xor(s1, 2);
        s2 += __shfl_xor(s2, 1); s2 += __shfl_xor(s2, 2);
        as_[i] = s1; ad_[i] = s2;
    }
    if (kq == 0) {
#pragma unroll
        for (int i = 0; i < 4; ++i) {
            int n = n0 + ng * 4 + i;
            if (n < N) { a_src[n] = as_[i]; a_dst[n] = ad_[i]; }
        }
    }
    {
        int n = n0 + t;
        if (n < N) deg[n] = 0;
    }
}

// K3: in-degree count; atomic return value = edge's rank within its destination.
__global__ __launch_bounds__(256) void k_count(const void* __restrict__ ei,
                                               const int* __restrict__ flag,
                                               int* __restrict__ deg,
                                               int* __restrict__ rank, int E) {
    int e = blockIdx.x * blockDim.x + threadIdx.x;
    if (e >= E) return;
    int is64 = *flag;
    int s, d;
    load_edge(ei, E, is64, e, s, d);
    rank[e] = atomicAdd(&deg[d], 1);
}

// K4a: per-block exclusive scan of deg -> rowptr (local), block sums -> bsum
__global__ __launch_bounds__(256) void k_scan_block(const int* __restrict__ deg,
                                                    int* __restrict__ rowptr,
                                                    int* __restrict__ bsum, int N) {
    __shared__ int sm[256];
    const int t = threadIdx.x;
    const int base = blockIdx.x * SCAN_ELEMS + t * 8;
    int v[8];
    int s = 0;
#pragma unroll
    for (int i = 0; i < 8; ++i) {
        v[i] = (base + i < N) ? deg[base + i] : 0;
        s += v[i];
    }
    sm[t] = s;
    __syncthreads();
    for (int off = 1; off < 256; off <<= 1) {
        int y = (t >= off) ? sm[t - off] : 0;
        __syncthreads();
        sm[t] += y;
        __syncthreads();
    }
    int run = sm[t] - s;
#pragma unroll
    for (int i = 0; i < 8; ++i) {
        if (base + i < N) rowptr[base + i] = run;
        run += v[i];
    }
    if (t == 255) bsum[blockIdx.x] = sm[255];
}

// K4b: scan the block sums in place (exclusive)
__global__ void k_scan_partials(int* __restrict__ bsum, int nb) {
    if (threadIdx.x == 0 && blockIdx.x == 0) {
        int run = 0;
        for (int b = 0; b < nb; ++b) {
            int t = bsum[b];
            bsum[b] = run;
            run += t;
        }
    }
}

// K4c: add block offsets; set rowptr[N]=E
__global__ __launch_bounds__(256) void k_scan_add(int* __restrict__ rowptr,
                                                  const int* __restrict__ bsum, int N, int E) {
    int i = blockIdx.x * blockDim.x + threadIdx.x;
    if (i == 0) rowptr[N] = E;
    if (i >= N) return;
    rowptr[i] += bsum[i / SCAN_ELEMS];
}

// K5: scatter edges into CSR (no atomics): pos = rowptr[d] + rank[e].
// One packed 8B nontemporal store per edge: (src, exp(logit)).
__global__ __launch_bounds__(256) void k_scatter(const void* __restrict__ ei,
                                                 const int* __restrict__ flag,
                                                 const float* __restrict__ a_src,
                                                 const float* __restrict__ a_dst,
                                                 const int* __restrict__ rowptr,
                                                 const int* __restrict__ rank,
                                                 unsigned long long* __restrict__ packed,
                                                 int E) {
    int e = blockIdx.x * blockDim.x + threadIdx.x;
    if (e >= E) return;
    int is64 = *flag;
    int s, d;
    load_edge(ei, E, is64, e, s, d);
    int pos = rowptr[d] + rank[e];
    float l = leaky(a_src[s] + a_dst[d]);
    float ev = __expf(fminf(l, 50.f));
    unsigned long long u = ((unsigned long long)__float_as_uint(ev) << 32) | (unsigned)s;
    __builtin_nontemporal_store(u, packed + pos);
}

// K6: fused per-node aggregation + elu + linear + log_softmax. One wave per
// node, 4 waves/block; 4 edge-slots x 16 channels, 3 channels/lane.
// h gathered in fp16 (2 cache lines per row). Unnormalized accumulation
// with precomputed ev; single pass, no max sweep.
__global__ __launch_bounds__(256) void k_gat_node(const int* __restrict__ rowptr,
                                                  const unsigned long long* __restrict__ packed,
                                                  const float* __restrict__ a_src,
                                                  const float* __restrict__ a_dst,
                                                  const __half* __restrict__ h2,
                                                  const float* __restrict__ gat_bias,
                                                  const float* __restrict__ lin_W,
                                                  const float* __restrict__ lin_b,
                                                  float* __restrict__ out, int N) {
    __shared__ float Wl[HID * OUT_CH];
    __shared__ float lb[OUT_CH];
    __shared__ float gb[HID];
    __shared__ float o_sm[4][HID];
    const int t = threadIdx.x;
    for (int i = t; i < HID * OUT_CH; i += 256) Wl[i] = lin_W[i];
    if (t < OUT_CH) lb[t] = lin_b[t];
    if (t >= 64 && t < 64 + HID) gb[t - 64] = gat_bias[t - 64];
    __syncthreads();

    const int wv = t >> 6;
    const int lane = t & 63;
    const int slot = lane >> 4;   // 0..3
    const int c = lane & 15;      // 0..15
    const int n = blockIdx.x * 4 + wv;
    const bool active = n < N;

    if (active) {
        const int base = rowptr[n];
        const int deg = rowptr[n + 1] - base;
        const float self_l = leaky(a_src[n] + a_dst[n]);
        const float ev_self = __expf(fminf(self_l, 50.f));

        const __half* hn = h2 + (size_t)n * HID;
        float acc0 = 0.f, acc1 = 0.f, acc2 = 0.f;
        if (slot == 0) {
            acc0 = ev_self * __half2float(hn[c]);
            acc1 = ev_self * __half2float(hn[c + 16]);
            acc2 = ev_self * __half2float(hn[c + 32]);
        }
        float evsum = 0.f;   // per-slot-group partial (identical within group)
#pragma unroll 4
        for (int j = slot; j < deg; j += 4) {
            unsigned long long pr = packed[base + j];
            int sj = (int)(unsigned)pr;
            float ev = __uint_as_float((unsigned)(pr >> 32));
            evsum += ev;
            const __half* hp = h2 + (size_t)sj * HID;
            acc0 += ev * __half2float(hp[c]);
            acc1 += ev * __half2float(hp[c + 16]);
            acc2 += ev * __half2float(hp[c + 32]);
        }
        // cross-slot reduction (values uniform within each 16-lane group)
        evsum += __shfl_xor(evsum, 16);
        evsum += __shfl_xor(evsum, 32);
        acc0 += __shfl_xor(acc0, 16);
        acc0 += __shfl_xor(acc0, 32);
        acc1 += __shfl_xor(acc1, 16);
        acc1 += __shfl_xor(acc1, 32);
        acc2 += __shfl_xor(acc2, 16);
        acc2 += __shfl_xor(acc2, 32);
        const float inv = 1.f / (evsum + ev_self);
        if (slot == 0) {
            o_sm[wv][c] = elu(acc0 * inv + gb[c]);
            o_sm[wv][c + 16] = elu(acc1 * inv + gb[c + 16]);
            o_sm[wv][c + 32] = elu(acc2 * inv + gb[c + 32]);
        }
    }
    __syncthreads();

    if (active && lane < OUT_CH) {
        float z = lb[lane];
        const float* o = o_sm[wv];
#pragma unroll
        for (int k = 0; k < HID; ++k) z += o[k] * Wl[k * OUT_CH + lane];
        float mx = z;
#pragma unroll
        for (int off = 8; off; off >>= 1) mx = fmaxf(mx, __shfl_xor(mx, off, 16));
        float ev = __expf(z - mx);
#pragma unroll
        for (int off = 8; off; off >>= 1) ev += __shfl_xor(ev, off, 16);
        float lse = mx + __logf(ev);
        out[(size_t)n * OUT_CH + lane] = z - lse;
    }
}

extern "C" void kernel_launch(void* const* d_in, const int* in_sizes, int n_in,
                              void* d_out, int out_size, void* d_ws, size_t ws_size,
                              hipStream_t stream) {
    const float* x = (const float*)d_in[0];
    const void* edge_index = d_in[1];
    const float* W = (const float*)d_in[2];
    const float* att_src = (const float*)d_in[3];
    const float* att_dst = (const float*)d_in[4];
    const float* gat_bias = (const float*)d_in[5];
    const float* lin_W = (const float*)d_in[6];
    const float* lin_b = (const float*)d_in[7];
    float* out = (float*)d_out;

    const int N = in_sizes[0] / IN_CH;
    const int E = in_sizes[1] / 2;

    __half* h2 = (__half*)d_ws;                    // N*48 halves (9.6MB)
    float* a_src = (float*)(h2 + (size_t)N * HID); // N  (byte offset N*96, 4/8-aligned)
    float* a_dst = a_src + N;                      // N
    int* rank = (int*)(a_dst + N);                 // E
    int* rowptr = rank + E;                        // N+1
    int* degbuf = rowptr + N + 1;                  // N
    int* bsum = degbuf + N;                        // 64
    int* flag = bsum + 64;                         // 1
    unsigned long long* packed =
        (unsigned long long*)(((uintptr_t)(flag + 1) + 7) & ~(uintptr_t)7);  // E x 8B

    const int nodeBlocks = (N + 255) / 256;
    const int edgeBlocks = (E + 255) / 256;
    const int scanBlocks = (N + SCAN_ELEMS - 1) / SCAN_ELEMS;

    k_detect<<<1, 64, 0, stream>>>((const unsigned*)edge_index, flag);
    k_xw<<<(N + BLK_NODES - 1) / BLK_NODES, 256, 0, stream>>>(x, W, att_src, att_dst,
                                                              h2, a_src, a_dst, degbuf, N);
    k_count<<<edgeBlocks, 256, 0, stream>>>(edge_index, flag, degbuf, rank, E);
    k_scan_block<<<scanBlocks, 256, 0, stream>>>(degbuf, rowptr, bsum, N);
    k_scan_partials<<<1, 64, 0, stream>>>(bsum, scanBlocks);
    k_scan_add<<<nodeBlocks, 256, 0, stream>>>(rowptr, bsum, N, E);
    k_scatter<<<edgeBlocks, 256, 0, stream>>>(edge_index, flag, a_src, a_dst, rowptr,
                                              rank, packed, E);
    k_gat_node<<<(N + 3) / 4, 256, 0, stream>>>(rowptr, packed, a_src, a_dst,
                                                h2, gat_bias, lin_W, lin_b, out, N);
}